// Round 19
// baseline (1107.614 us; speedup 1.0000x reference)
//
#include <hip/hip_runtime.h>

#define BB 16
#define LL 512
#define DD 512
#define ROWS (BB*LL)   // 8192

// wbf element offsets (shared by host + cvt_all)
#define W_IN  0
#define W_XP  2097152
#define W_DT  2359296
#define W_OUT 2621440
#define W_FF1 3670016
#define W_FF2 5767168

typedef unsigned short u16;
typedef __attribute__((ext_vector_type(8))) short short8;
typedef __attribute__((ext_vector_type(4))) float f32x4;
typedef __attribute__((ext_vector_type(4))) unsigned short u16x4;

__device__ __forceinline__ float b2f(u16 u) {
    return __uint_as_float(((unsigned int)u) << 16);
}
__device__ __forceinline__ u16 f2b(float f) {
    unsigned int u = __float_as_uint(f);
    u += 0x7FFFu + ((u >> 16) & 1u);
    return (u16)(u >> 16);
}
__device__ __forceinline__ float ld1(const void* p, size_t i, int f32) {
    return f32 ? ((const float*)p)[i] : b2f(((const u16*)p)[i]);
}
// extract bf16 element j (compile-time) from a uint4 of 8 bf16
__device__ __forceinline__ float bf_elem(uint4 v, int j) {
    unsigned w = ((const unsigned*)&v)[j >> 1];
    return __uint_as_float((j & 1) ? (w & 0xFFFF0000u) : (w << 16));
}
// sum across the 16-lane group via DPP (pure VALU, all lanes get the sum)
__device__ __forceinline__ float red16(float x) {
    int v = __float_as_int(x);
    x += __int_as_float(__builtin_amdgcn_update_dpp(0, v, 0xB1, 0xF, 0xF, true));  // quad xor1
    v = __float_as_int(x);
    x += __int_as_float(__builtin_amdgcn_update_dpp(0, v, 0x4E, 0xF, 0xF, true));  // quad xor2
    v = __float_as_int(x);
    x += __int_as_float(__builtin_amdgcn_update_dpp(0, v, 0x141, 0xF, 0xF, true)); // row_half_mirror
    v = __float_as_int(x);
    x += __int_as_float(__builtin_amdgcn_update_dpp(0, v, 0x140, 0xF, 0xF, true)); // row_mirror
    return x;
}
// async global->LDS 16B: per-lane global src, wave-uniform LDS base (+lane*16 implicit)
__device__ __forceinline__ void gld16(const u16* g, u16* l) {
    __builtin_amdgcn_global_load_lds(
        (const __attribute__((address_space(1))) unsigned int*)g,
        (__attribute__((address_space(3))) unsigned int*)l, 16, 0, 0);
}

// Input dtype detector (fp32 vs bf16), see R2 notes.
__global__ void detect(const u16* __restrict__ x, int* __restrict__ flag)
{
    __shared__ int s;
    if (threadIdx.x == 0) s = 0;
    __syncthreads();
    u16 v = x[2 * threadIdx.x] & 0x7FFFu;
    if ((v & 0x7F80u) >= 0x5000u) atomicOr(&s, 1);
    __syncthreads();
    if (threadIdx.x == 0) *flag = s;
}

// Fused prologue: all input conversions in one dispatch (segments 256-aligned,
// per-block-uniform branch). Scalar-coalesced pattern (Round-13 lesson).
__global__ __launch_bounds__(256)
void cvt_all(const void* __restrict__ X, float* __restrict__ acc, u16* __restrict__ cur,
             const void* __restrict__ in_w, const void* __restrict__ f1w,
             const void* __restrict__ f2w, const void* __restrict__ xp,
             const void* __restrict__ dw, const void* __restrict__ ow,
             u16* __restrict__ wbf, const int* __restrict__ flag)
{
    const int f = *flag;
    size_t t = (size_t)blockIdx.x * 256 + threadIdx.x;
    if (t < 4194304) {                       // X -> acc f32 + cur bf16
        float v = ld1(X, t, f);
        acc[t] = v; cur[t] = f2b(v);
        return;
    }
    t -= 4194304;
    if (t < 2097152) { wbf[W_IN  + t] = f2b(ld1(in_w, t, f)); return; }
    t -= 2097152;
    if (t < 2097152) { wbf[W_FF1 + t] = f2b(ld1(f1w, t, f)); return; }
    t -= 2097152;
    if (t < 2097152) { wbf[W_FF2 + t] = f2b(ld1(f2w, t, f)); return; }
    t -= 2097152;
    if (t < 262144) {                        // XP2 block-diag
        int i = (int)t;
        int e = i >> 17, r = (i >> 10) & 127, c = i & 1023;
        int dir = r >> 6, n = r & 63;
        float v = ((c >> 9) == dir)
            ? ld1(xp, ((size_t)(e*2 + dir)*64 + n)*512 + (c & 511), f) : 0.f;
        wbf[W_XP + i] = f2b(v);
        return;
    }
    t -= 262144;
    if (t < 262144) {                        // DT2 block-diag
        int i = (int)t;
        int e = i >> 17, r = (i >> 7) & 1023, c = i & 127;
        int dir = r >> 9, d = r & 511;
        float v = 0.f;
        if (dir == 0 && c < 32)
            v = ld1(dw, ((size_t)(e*2)*512 + d)*32 + c, f);
        else if (dir == 1 && c >= 64 && c < 96)
            v = ld1(dw, ((size_t)(e*2 + 1)*512 + d)*32 + (c - 64), f);
        wbf[W_DT + i] = f2b(v);
        return;
    }
    t -= 262144;
    {                                        // OUT2 K-concat (1048576)
        int i = (int)t;
        int e = i >> 19, rest = i & 524287;
        int d = rest >> 10, c = rest & 1023;
        int dir = c >> 9;
        wbf[W_OUT + i] = f2b(ld1(ow, ((size_t)(e*2 + dir)*512 + d)*512 + (c & 511), f));
    }
}

// Sum 4 split-K partials -> bf16 proj. psum [4][8192][128] f32, coalesced.
__global__ __launch_bounds__(256)
void ksum(const float* __restrict__ psum, u16* __restrict__ proj)
{
    int i = blockIdx.x * 256 + threadIdx.x;   // 0..1048575
    float s = psum[i] + psum[i + 1048576] + psum[i + 2097152] + psum[i + 3145728];
    proj[i] = f2b(s);
}

// MFMA GEMM: C[M,N] = act(A[M,K] @ W[N,K]^T + bias[boff + (brow?row:col)]).
// A,W bf16 row-major, lda=K. 128x128 tile, 4 waves, BK=64.
// Staging via global_load_lds w16, linear [128][64] LDS; T2 XOR-swizzle both sides.
// Split-K modes (K/kcnt must be multiple of 64):
//  kcnt>1, Cf2==null: block z writes raw f32 partial to Cf + z*M*N (gemm2 psum mode).
//  kcnt>1, Cf2!=null: z=0 runs the NORMAL epilogue on its K-slice;
//                     z>0 writes raw f32 partial to Cf2 (consumer sums it; act must be 0).
// accum? Cf+=v : (Cf? Cf=v : bf16 stores). Cb: row-major [M][N]. CbT: transposed [N][M].
// act:0 none,1 softplus,2 gelu(exact),3 silu iff (col&512) [xz z-halves]
__global__ __launch_bounds__(256)
void gemm_mfma(const u16* __restrict__ A, const u16* __restrict__ W,
               float* __restrict__ Cf, u16* __restrict__ Cb, u16* __restrict__ CbT,
               float* __restrict__ Cf2,
               int M, int N, int K,
               const void* __restrict__ bias, size_t boff, int brow, int act, int accum,
               int kcnt, const int* __restrict__ flag)
{
    const int f = *flag;
    __shared__ u16 As[128][64];
    __shared__ u16 Ws[128][64];
    const int tid  = threadIdx.x;
    const int lane = tid & 63;
    const int wid  = tid >> 6;
    const int wr   = (wid >> 1) * 64;
    const int wc   = (wid & 1) * 64;
    const int row0 = blockIdx.y * 128;
    const int col0 = blockIdx.x * 128;
    const int mrow = lane & 15;
    const int kq   = (lane >> 4) * 8;
    const int swz  = (mrow & 7) << 3;
    const int kq0  = kq ^ swz;
    const int kq1  = (kq + 32) ^ swz;
    const int srow = wid * 32 + (lane >> 3);
    const int scol = (((lane & 7) ^ (lane >> 3)) & 7) * 8;
    const u16* gA = A + (size_t)(row0 + srow) * K + scol;
    const u16* gW = W + (size_t)(col0 + srow) * K + scol;
    u16* lA = &As[wid * 32][0];   // wave-uniform
    u16* lW = &Ws[wid * 32][0];
    const int kn = K / kcnt;
    const int kb = blockIdx.z * kn;

    f32x4 acc[4][4] = {};
    for (int k0 = kb; k0 < kb + kn; k0 += 64) {
        #pragma unroll
        for (int q = 0; q < 4; ++q) {
            gld16(gA + k0 + (size_t)(8 * q) * K, lA + 512 * q);
            gld16(gW + k0 + (size_t)(8 * q) * K, lW + 512 * q);
        }
        __syncthreads();   // drains vmcnt -> LDS writes visible
        #pragma unroll
        for (int kk = 0; kk < 2; ++kk) {
            const int kc = kk ? kq1 : kq0;
            short8 af[4], bfr[4];
            #pragma unroll
            for (int mi = 0; mi < 4; ++mi)
                af[mi] = *(const short8*)&As[wr + mi*16 + mrow][kc];
            #pragma unroll
            for (int ni = 0; ni < 4; ++ni)
                bfr[ni] = *(const short8*)&Ws[wc + ni*16 + mrow][kc];
            #pragma unroll
            for (int mi = 0; mi < 4; ++mi)
                #pragma unroll
                for (int ni = 0; ni < 4; ++ni)
                    acc[mi][ni] = __builtin_amdgcn_mfma_f32_16x16x32_bf16(
                        af[mi], bfr[ni], acc[mi][ni], 0, 0, 0);
        }
        __syncthreads();
    }
    const int drow = (lane >> 4) * 4;
    const int dcol = lane & 15;
    // raw-partial paths (no bias/act)
    if (kcnt > 1 && blockIdx.z > 0 && Cf2) {
        #pragma unroll
        for (int mi = 0; mi < 4; ++mi)
            #pragma unroll
            for (int ni = 0; ni < 4; ++ni) {
                const int rowb = row0 + wr + mi*16 + drow;
                const int col  = col0 + wc + ni*16 + dcol;
                #pragma unroll
                for (int r = 0; r < 4; ++r)
                    Cf2[(size_t)(rowb + r) * N + col] = acc[mi][ni][r];
            }
        return;
    }
    float* Cfz = Cf;
    if (kcnt > 1 && !Cf2) Cfz = Cf + (size_t)blockIdx.z * ((size_t)M * N);
    #pragma unroll
    for (int mi = 0; mi < 4; ++mi) {
        #pragma unroll
        for (int ni = 0; ni < 4; ++ni) {
            const int rowb = row0 + wr + mi*16 + drow;
            const int col  = col0 + wc + ni*16 + dcol;
            float vv[4];
            #pragma unroll
            for (int r = 0; r < 4; ++r) {
                float bv = bias ? ld1(bias, boff + (brow ? (size_t)(rowb + r)
                                                         : (size_t)col), f) : 0.f;
                float v = acc[mi][ni][r] + bv;
                if (act == 1) v = (v > 15.f) ? v : log1pf(__expf(v));
                else if (act == 2) v = 0.5f * v * (1.f + erff(v * 0.70710678118f));
                else if (act == 3) { if (col & 512) v = v / (1.f + __expf(-v)); }
                vv[r] = v;
            }
            if (accum) {
                #pragma unroll
                for (int r = 0; r < 4; ++r)
                    Cf[(size_t)(rowb + r) * N + col] += vv[r];
            } else if (Cf) {
                #pragma unroll
                for (int r = 0; r < 4; ++r)
                    Cfz[(size_t)(rowb + r) * N + col] = vv[r];
            } else {
                if (Cb) {
                    #pragma unroll
                    for (int r = 0; r < 4; ++r)
                        Cb[(size_t)(rowb + r) * N + col] = f2b(vv[r]);
                }
                if (CbT) {
                    u16x4 pk;
                    #pragma unroll
                    for (int r = 0; r < 4; ++r) pk[r] = f2b(vv[r]);
                    *(u16x4*)(CbT + (size_t)col * M + rowb) = pk;
                }
            }
        }
    }
}

// Both-dirs conv + silu on x-cols only (z-cols already silu'd by gemm1 act=3).
// xz_both [ROWS][2048]: 0..511 x_f | 512..1023 z_f | 1024..1535 x_r | 1536..2047 z_r
__global__ __launch_bounds__(256)
void conv_both(const u16* __restrict__ xz, const void* __restrict__ cw,
               const void* __restrict__ cb, u16* __restrict__ xc, int e,
               const int* __restrict__ flag)
{
    const int f = *flag;
    int idx = blockIdx.x * 256 + threadIdx.x;   // ROWS*1024
    int row = idx >> 10;
    int c = idx & 1023;
    int dir = c >> 9, d = c & 511;
    int l = row & (LL - 1);
    size_t base = (size_t)row * 2048 + dir * 1024;
    float xcur = b2f(xz[base + d]);
    int dsign = dir ? 1 : -1;
    int ln = l + dsign;
    float xnb = (ln >= 0 && ln < LL) ? b2f(xz[base + dsign*2048 + d]) : 0.f;
    size_t co = (size_t)(e*2 + dir) * 1024 + 2*d;
    float v = ld1(cw, co, f) * xnb + ld1(cw, co + 1, f) * xcur
            + ld1(cb, (size_t)(e*2 + dir)*512 + d, f);
    xc[(size_t)row * 1024 + c] = f2b(v / (1.f + __expf(-v)));
}

// [8192][C] -> [C][8192] bf16 transpose, 64x64 LDS tiles. grid (C/64, 128).
__global__ __launch_bounds__(256)
void transp(const u16* __restrict__ src, u16* __restrict__ dst, int C)
{
    __shared__ u16 t[64][72];
    const int c0 = blockIdx.x * 64, r0 = blockIdx.y * 64;
    const int rr = threadIdx.x >> 3, cc = (threadIdx.x & 7) * 8;
    #pragma unroll
    for (int i = 0; i < 2; ++i) {
        uint4 v = *(const uint4*)(src + (size_t)(r0 + rr + i*32) * C + c0 + cc);
        *(uint4*)&t[rr + i*32][cc] = v;
    }
    __syncthreads();
    const int tc = threadIdx.x >> 3, tr = (threadIdx.x & 7) * 8;
    #pragma unroll
    for (int i = 0; i < 2; ++i) {
        u16 tmp[8];
        #pragma unroll
        for (int j = 0; j < 8; ++j) tmp[j] = t[tr + j][tc + i*32];
        *(uint4*)(dst + (size_t)(c0 + tc + i*32) * 8192 + r0 + tr) = *(uint4*)tmp;
    }
}

// Direction-templated scan body (Round-3 verified form): depth-1 prefetch with
// loads issued BEFORE the serial chunk compute; 8-step chunks, 16B vector loads,
// DPP reduction, one masked store per chunk (lane j holds step j's output).
template<int DIR>
__device__ __forceinline__ void scan_dir(
    const u16* __restrict__ dtp, const u16* __restrict__ xcp,
    const u16* __restrict__ Bp, const u16* __restrict__ Cp,
    const u16* __restrict__ zp, u16* __restrict__ gp,
    float Av, float Dv, int lane)
{
    float h = 0.f;
    int lb = DIR ? (LL - 8) : 0;
    const int stp = DIR ? -8 : 8;
    uint4 d8 = *(const uint4*)(dtp + lb);
    uint4 x8 = *(const uint4*)(xcp + lb);
    uint4 B8 = *(const uint4*)(Bp + lb);
    uint4 C8 = *(const uint4*)(Cp + lb);
    for (int it = 0; it < LL / 8; ++it) {
        const int lbn = lb + stp;
        uint4 nd = d8, nx = x8, nB = B8, nC = C8;
        if (it < LL / 8 - 1) {
            nd = *(const uint4*)(dtp + lbn);
            nx = *(const uint4*)(xcp + lbn);
            nB = *(const uint4*)(Bp + lbn);
            nC = *(const uint4*)(Cp + lbn);
        }
        float keep = 0.f;
        #pragma unroll
        for (int jj = 0; jj < 8; ++jj) {
            const int j = DIR ? (7 - jj) : jj;
            float dtv = bf_elem(d8, j);
            float xv  = bf_elem(x8, j);
            float Bn  = bf_elem(B8, j);
            float Cn  = bf_elem(C8, j);
            h = __expf(dtv * Av) * h + (dtv * xv) * Bn;
            float c = red16(h * Cn) + Dv * xv;
            keep = (lane == j) ? c : keep;
        }
        if (lane < 8) {
            float zs = b2f(zp[(lb + lane) * 2048]);   // pre-silu'd z (gemm1 act=3)
            gp[(lb + lane) * 1024] = f2b(keep * zs);
        }
        d8 = nd; x8 = nx; B8 = nB; C8 = nC;
        lb = lbn;
    }
}

// Both-dirs selective scan. Inputs L-contiguous: dtT/xcT [1024][8192], projT [128][8192].
// z read scalar from xz (row-major). Output g row-major [8192][1024]. 1024 blocks.
__global__ __launch_bounds__(256)
void ssm_scan(u16* __restrict__ g, const u16* __restrict__ dtT,
              const u16* __restrict__ xcT, const u16* __restrict__ projT,
              const u16* __restrict__ xz,
              const void* __restrict__ A_log, const void* __restrict__ Dsk,
              int e, const int* __restrict__ flag)
{
    const int f = *flag;
    const int lane = threadIdx.x & 15;
    const int gg = blockIdx.x * 16 + (threadIdx.x >> 4);   // 0..16383
    const int dir = gg >> 13;
    const int rem = gg & 8191;
    const int b = rem >> 9, d = rem & 511;
    const int ed = e * 2 + dir;
    const float Av = -__expf(ld1(A_log, (size_t)ed * 8192 + d * 16 + lane, f));
    const float Dv = ld1(Dsk, (size_t)ed * 512 + d, f);
    const int col = dir * 512 + d;
    const size_t tb = (size_t)col * 8192 + b * 512;
    const u16* dtp = dtT + tb;
    const u16* xcp = xcT + tb;
    const u16* Bp  = projT + (size_t)(dir * 64 + 32 + lane) * 8192 + b * 512;
    const u16* Cp  = Bp + (size_t)16 * 8192;
    u16* gp = g + (size_t)b * LL * 1024 + col;
    const u16* zp = xz + (size_t)b * LL * 2048 + dir * 1024 + 512 + d;
    if (dir == 0) scan_dir<0>(dtp, xcp, Bp, Cp, zp, gp, Av, Dv, lane);
    else          scan_dir<1>(dtp, xcp, Bp, Cp, zp, gp, Av, Dv, lane);
}

// Row LayerNorm; optional extra f32 input Xf2 (split-K partial) and f32
// side-output accf (pre-rounding, replaces acc_init).
__global__ __launch_bounds__(256)
void lnorm(const u16* __restrict__ Xb, const float* __restrict__ Xf,
           const float* __restrict__ Xf2,
           const void* __restrict__ w, size_t wo, const void* __restrict__ b, size_t bo,
           void* __restrict__ out, int omode, float* __restrict__ accf,
           const int* __restrict__ flag)
{
    const int f = *flag;
    int wid = (blockIdx.x * 256 + threadIdx.x) >> 6;
    int lane = threadIdx.x & 63;
    size_t base = (size_t)wid * DD;
    float v[8];
    float s = 0.f;
    #pragma unroll
    for (int i = 0; i < 8; ++i) {
        int c = lane + i*64;
        float t = 0.f;
        if (Xb) t += b2f(Xb[base + c]);
        if (Xf) t += Xf[base + c];
        if (Xf2) t += Xf2[base + c];
        v[i] = t; s += t;
    }
    #pragma unroll
    for (int off = 32; off > 0; off >>= 1) s += __shfl_xor(s, off);
    float mean = s * (1.f/512.f);
    float var = 0.f;
    #pragma unroll
    for (int i = 0; i < 8; ++i) { float dlt = v[i] - mean; var += dlt*dlt; }
    #pragma unroll
    for (int off = 32; off > 0; off >>= 1) var += __shfl_xor(var, off);
    float rstd = rsqrtf(var * (1.f/512.f) + 1e-5f);
    #pragma unroll
    for (int i = 0; i < 8; ++i) {
        int c = lane + i*64;
        float o = (v[i] - mean) * rstd * ld1(w, wo + c, f) + ld1(b, bo + c, f);
        if (omode && f) ((float*)out)[base + c] = o;
        else            ((u16*)out)[base + c] = f2b(o);
        if (accf) accf[base + c] = o;
    }
}

extern "C" void kernel_launch(void* const* d_in, const int* in_sizes, int n_in,
                              void* d_out, int out_size, void* d_ws, size_t ws_size,
                              hipStream_t stream)
{
    (void)in_sizes; (void)n_in; (void)out_size; (void)ws_size;
    const void* X       = d_in[0];
    const void* in_w    = d_in[1];
    const void* conv_w  = d_in[2];
    const void* conv_b  = d_in[3];
    const void* xproj_w = d_in[4];
    const void* dt_w    = d_in[5];
    const void* dt_b    = d_in[6];
    const void* A_log   = d_in[7];
    const void* D_skip  = d_in[8];
    const void* out_w   = d_in[9];
    const void* ffn1_w  = d_in[10];
    const void* ffn1_b  = d_in[11];
    const void* ffn2_w  = d_in[12];
    const void* ffn2_b  = d_in[13];
    const void* n1_w    = d_in[14];
    const void* n1_b    = d_in[15];
    const void* n2_w    = d_in[16];
    const void* n2_b    = d_in[17];
    const void* fn_w    = d_in[18];
    const void* fn_b    = d_in[19];

    // Workspace (~123 MB):
    // acc f32 @0 (16M) | cur bf16 @16M (8M) | xz @24M (32M; ffn: ffh)
    // xc @56M (16M; after gemm#2: dtT overlay; ffn: y2 f32)
    // g @72M (16M; gemm2 split-K psum f32; ffn: x1) | proj @88M (2M) | flag @90M
    // wbf @90M+4K (15M) | xcT @105M (16M; after scan: split-K partial psk f32)
    // projT @121M (2M)
    char* p = (char*)d_ws;
    float* acc   = (float*)(p);
    u16*   cur   = (u16*)(p + 16777216);
    u16*   xz    = (u16*)(p + 25165824);
    u16*   xc    = (u16*)(p + 58720256);
    u16*   dtT   = (u16*)(p + 58720256);   // overlays xc (xc dead after gemm#2/3)
    u16*   g     = (u16*)(p + 75497472);
    u16*   proj  = (u16*)(p + 92274688);
    int*   flag  = (int*)(p + 94371840);
    u16*   wbf   = (u16*)(p + 94375936);
    u16*   xcT   = (u16*)(p + 110104576);
    u16*   projT = (u16*)(p + 126881792);
    u16*   ffh   = xz;
    float* y2    = (float*)xc;
    u16*   x1    = g;
    float* psum  = (float*)g;     // 4x8192x128 f32 = 16MB, g dead until scan
    float* psk   = (float*)xcT;   // 8192x512 f32 = 16MB, xcT dead after scan

    detect<<<1, 512, 0, stream>>>((const u16*)X, flag);
    // fused prologue: 12,058,624 threads
    cvt_all<<<47104, 256, 0, stream>>>(X, acc, cur, in_w, ffn1_w, ffn2_w,
                                       xproj_w, dt_w, out_w, wbf, flag);

    for (int e = 0; e < 2; ++e) {
        size_t eo = (size_t)e * 512;
        // xz_both = cur @ [in_f; in_r]^T : [8192,2048]; act=3 silu's z-halves in-place
        gemm_mfma<<<dim3(16,64), 256, 0, stream>>>(
            cur, wbf + W_IN + (size_t)e*1048576, nullptr, xz, nullptr, nullptr,
            ROWS, 2048, 512, nullptr, 0, 0, 3, 0, 1, flag);
        conv_both<<<ROWS*1024/256, 256, 0, stream>>>(xz, conv_w, conv_b, xc, e, flag);
        // xcT = xc^T : [1024][8192]
        transp<<<dim3(16,128), 256, 0, stream>>>(xc, xcT, 1024);
        // proj_both = xc_both @ XP2^T : [8192,128], split-K=4 into psum (g region)
        gemm_mfma<<<dim3(1,64,4), 256, 0, stream>>>(
            xc, wbf + W_XP + (size_t)e*131072, psum, nullptr, nullptr, nullptr,
            ROWS, 128, 1024, nullptr, 0, 0, 0, 0, 4, flag);
        ksum<<<4096, 256, 0, stream>>>(psum, proj);
        transp<<<dim3(2,128), 256, 0, stream>>>(proj, projT, 128);
        // dtT = softplus(DT2 @ proj^T + dt_b[row]) : [1024][8192] ROW-MAJOR directly
        // (re-associated transpose: coalesced stores; bias per row)
        gemm_mfma<<<dim3(64,8), 256, 0, stream>>>(
            wbf + W_DT + (size_t)e*131072, proj, nullptr, dtT, nullptr, nullptr,
            1024, ROWS, 128, dt_b, (size_t)e*1024, 1, 1, 0, 1, flag);
        ssm_scan<<<1024, 256, 0, stream>>>(g, dtT, xcT, projT, xz,
                                           A_log, D_skip, e, flag);
        // acc += g_both @ OUT2^T : [8192,512], split-K=2 (z=0 accum, z=1 -> psk)
        gemm_mfma<<<dim3(4,64,2), 256, 0, stream>>>(
            g, wbf + W_OUT + (size_t)e*524288, acc, nullptr, nullptr, psk,
            ROWS, 512, 1024, nullptr, 0, 0, 0, 1, 2, flag);
        // lnorm1 sums acc + psk
        lnorm<<<2048, 256, 0, stream>>>(nullptr, acc, psk, n1_w, eo, n1_b, eo,
                                        x1, 0, nullptr, flag);
        gemm_mfma<<<dim3(16,64), 256, 0, stream>>>(
            x1, wbf + W_FF1 + (size_t)e*1048576, nullptr, ffh, nullptr, nullptr,
            ROWS, 2048, 512, ffn1_b, (size_t)e*2048, 0, 2, 0, 1, flag);
        // y2 = ffh @ FF2^T + bias : split-K=2 (z=0 -> y2 with bias, z=1 -> psk)
        gemm_mfma<<<dim3(4,64,2), 256, 0, stream>>>(
            ffh, wbf + W_FF2 + (size_t)e*1048576, y2, nullptr, nullptr, psk,
            ROWS, 512, 2048, ffn2_b, eo, 0, 0, 0, 2, flag);
        // lnorm2 sums x1 + y2 + psk; e=0: also write acc f32 (replaces acc_init)
        lnorm<<<2048, 256, 0, stream>>>(x1, y2, psk, n2_w, eo, n2_b, eo, cur, 0,
                                        (e == 0) ? acc : nullptr, flag);
    }
    lnorm<<<2048, 256, 0, stream>>>(cur, nullptr, nullptr, fn_w, 0, fn_b, 0,
                                    d_out, 1, nullptr, flag);
}

// Round 20
// 1045.975 us; speedup vs baseline: 1.0589x; 1.0589x over previous
//
#include <hip/hip_runtime.h>

#define BB 16
#define LL 512
#define DD 512
#define ROWS (BB*LL)   // 8192

// wbf element offsets (shared by host + cvt_all)
#define W_IN  0
#define W_XP  2097152
#define W_DT  2359296
#define W_OUT 2621440
#define W_FF1 3670016
#define W_FF2 5767168

typedef unsigned short u16;
typedef __attribute__((ext_vector_type(8))) short short8;
typedef __attribute__((ext_vector_type(4))) float f32x4;
typedef __attribute__((ext_vector_type(4))) unsigned short u16x4;

__device__ __forceinline__ float b2f(u16 u) {
    return __uint_as_float(((unsigned int)u) << 16);
}
__device__ __forceinline__ u16 f2b(float f) {
    unsigned int u = __float_as_uint(f);
    u += 0x7FFFu + ((u >> 16) & 1u);
    return (u16)(u >> 16);
}
__device__ __forceinline__ float ld1(const void* p, size_t i, int f32) {
    return f32 ? ((const float*)p)[i] : b2f(((const u16*)p)[i]);
}
// extract bf16 element j (compile-time) from a uint4 of 8 bf16
__device__ __forceinline__ float bf_elem(uint4 v, int j) {
    unsigned w = ((const unsigned*)&v)[j >> 1];
    return __uint_as_float((j & 1) ? (w & 0xFFFF0000u) : (w << 16));
}
// sum across the 16-lane group via DPP (pure VALU, all lanes get the sum)
__device__ __forceinline__ float red16(float x) {
    int v = __float_as_int(x);
    x += __int_as_float(__builtin_amdgcn_update_dpp(0, v, 0xB1, 0xF, 0xF, true));  // quad xor1
    v = __float_as_int(x);
    x += __int_as_float(__builtin_amdgcn_update_dpp(0, v, 0x4E, 0xF, 0xF, true));  // quad xor2
    v = __float_as_int(x);
    x += __int_as_float(__builtin_amdgcn_update_dpp(0, v, 0x141, 0xF, 0xF, true)); // row_half_mirror
    v = __float_as_int(x);
    x += __int_as_float(__builtin_amdgcn_update_dpp(0, v, 0x140, 0xF, 0xF, true)); // row_mirror
    return x;
}
// async global->LDS 16B: per-lane global src, wave-uniform LDS base (+lane*16 implicit)
__device__ __forceinline__ void gld16(const u16* g, u16* l) {
    __builtin_amdgcn_global_load_lds(
        (const __attribute__((address_space(1))) unsigned int*)g,
        (__attribute__((address_space(3))) unsigned int*)l, 16, 0, 0);
}

// Input dtype detector (fp32 vs bf16), see R2 notes.
__global__ void detect(const u16* __restrict__ x, int* __restrict__ flag)
{
    __shared__ int s;
    if (threadIdx.x == 0) s = 0;
    __syncthreads();
    u16 v = x[2 * threadIdx.x] & 0x7FFFu;
    if ((v & 0x7F80u) >= 0x5000u) atomicOr(&s, 1);
    __syncthreads();
    if (threadIdx.x == 0) *flag = s;
}

// Fused prologue: all input conversions in one dispatch (segments 256-aligned,
// per-block-uniform branch). Scalar-coalesced pattern (Round-13 lesson).
__global__ __launch_bounds__(256)
void cvt_all(const void* __restrict__ X, float* __restrict__ acc, u16* __restrict__ cur,
             const void* __restrict__ in_w, const void* __restrict__ f1w,
             const void* __restrict__ f2w, const void* __restrict__ xp,
             const void* __restrict__ dw, const void* __restrict__ ow,
             u16* __restrict__ wbf, const int* __restrict__ flag)
{
    const int f = *flag;
    size_t t = (size_t)blockIdx.x * 256 + threadIdx.x;
    if (t < 4194304) {                       // X -> acc f32 + cur bf16
        float v = ld1(X, t, f);
        acc[t] = v; cur[t] = f2b(v);
        return;
    }
    t -= 4194304;
    if (t < 2097152) { wbf[W_IN  + t] = f2b(ld1(in_w, t, f)); return; }
    t -= 2097152;
    if (t < 2097152) { wbf[W_FF1 + t] = f2b(ld1(f1w, t, f)); return; }
    t -= 2097152;
    if (t < 2097152) { wbf[W_FF2 + t] = f2b(ld1(f2w, t, f)); return; }
    t -= 2097152;
    if (t < 262144) {                        // XP2 block-diag
        int i = (int)t;
        int e = i >> 17, r = (i >> 10) & 127, c = i & 1023;
        int dir = r >> 6, n = r & 63;
        float v = ((c >> 9) == dir)
            ? ld1(xp, ((size_t)(e*2 + dir)*64 + n)*512 + (c & 511), f) : 0.f;
        wbf[W_XP + i] = f2b(v);
        return;
    }
    t -= 262144;
    if (t < 262144) {                        // DT2 block-diag
        int i = (int)t;
        int e = i >> 17, r = (i >> 7) & 1023, c = i & 127;
        int dir = r >> 9, d = r & 511;
        float v = 0.f;
        if (dir == 0 && c < 32)
            v = ld1(dw, ((size_t)(e*2)*512 + d)*32 + c, f);
        else if (dir == 1 && c >= 64 && c < 96)
            v = ld1(dw, ((size_t)(e*2 + 1)*512 + d)*32 + (c - 64), f);
        wbf[W_DT + i] = f2b(v);
        return;
    }
    t -= 262144;
    {                                        // OUT2 K-concat (1048576)
        int i = (int)t;
        int e = i >> 19, rest = i & 524287;
        int d = rest >> 10, c = rest & 1023;
        int dir = c >> 9;
        wbf[W_OUT + i] = f2b(ld1(ow, ((size_t)(e*2 + dir)*512 + d)*512 + (c & 511), f));
    }
}

// Sum 4 split-K partials -> bf16 proj. psum [4][8192][128] f32, coalesced.
__global__ __launch_bounds__(256)
void ksum(const float* __restrict__ psum, u16* __restrict__ proj)
{
    int i = blockIdx.x * 256 + threadIdx.x;   // 0..1048575
    float s = psum[i] + psum[i + 1048576] + psum[i + 2097152] + psum[i + 3145728];
    proj[i] = f2b(s);
}

// MFMA GEMM: C[M,N] = act(A[M,K] @ W[N,K]^T + bias[boff+c]). A,W bf16 row-major, lda=K.
// 128x128 tile, 4 waves (64x64, 4x4 MFMA grid), BK=64.
// Staging via global_load_lds w16, linear [128][64] LDS; T2 XOR-swizzle both sides.
// Split-K modes (K/kcnt must be multiple of 64):
//  kcnt>1, Cf2==null: block z writes raw f32 partial to Cf + z*M*N (gemm2 psum mode).
//  kcnt>1, Cf2!=null: z=0 runs the NORMAL epilogue (bias/act/accum/Cf) on its K-slice;
//                     z>0 writes raw f32 partial to Cf2 (consumer sums it; act must be 0).
// accum? Cf+=v : (Cf? Cf=v : bf16 stores). Cb: row-major [M][N]. CbT: transposed [N][M].
// act:0 none,1 softplus,2 gelu(exact)
__global__ __launch_bounds__(256)
void gemm_mfma(const u16* __restrict__ A, const u16* __restrict__ W,
               float* __restrict__ Cf, u16* __restrict__ Cb, u16* __restrict__ CbT,
               float* __restrict__ Cf2,
               int M, int N, int K,
               const void* __restrict__ bias, size_t boff, int act, int accum,
               int kcnt, const int* __restrict__ flag)
{
    const int f = *flag;
    __shared__ u16 As[128][64];
    __shared__ u16 Ws[128][64];
    const int tid  = threadIdx.x;
    const int lane = tid & 63;
    const int wid  = tid >> 6;
    const int wr   = (wid >> 1) * 64;
    const int wc   = (wid & 1) * 64;
    const int row0 = blockIdx.y * 128;
    const int col0 = blockIdx.x * 128;
    const int mrow = lane & 15;
    const int kq   = (lane >> 4) * 8;
    const int swz  = (mrow & 7) << 3;
    const int kq0  = kq ^ swz;
    const int kq1  = (kq + 32) ^ swz;
    const int srow = wid * 32 + (lane >> 3);
    const int scol = (((lane & 7) ^ (lane >> 3)) & 7) * 8;
    const u16* gA = A + (size_t)(row0 + srow) * K + scol;
    const u16* gW = W + (size_t)(col0 + srow) * K + scol;
    u16* lA = &As[wid * 32][0];   // wave-uniform
    u16* lW = &Ws[wid * 32][0];
    const int kn = K / kcnt;
    const int kb = blockIdx.z * kn;

    f32x4 acc[4][4] = {};
    for (int k0 = kb; k0 < kb + kn; k0 += 64) {
        #pragma unroll
        for (int q = 0; q < 4; ++q) {
            gld16(gA + k0 + (size_t)(8 * q) * K, lA + 512 * q);
            gld16(gW + k0 + (size_t)(8 * q) * K, lW + 512 * q);
        }
        __syncthreads();   // drains vmcnt -> LDS writes visible
        #pragma unroll
        for (int kk = 0; kk < 2; ++kk) {
            const int kc = kk ? kq1 : kq0;
            short8 af[4], bfr[4];
            #pragma unroll
            for (int mi = 0; mi < 4; ++mi)
                af[mi] = *(const short8*)&As[wr + mi*16 + mrow][kc];
            #pragma unroll
            for (int ni = 0; ni < 4; ++ni)
                bfr[ni] = *(const short8*)&Ws[wc + ni*16 + mrow][kc];
            #pragma unroll
            for (int mi = 0; mi < 4; ++mi)
                #pragma unroll
                for (int ni = 0; ni < 4; ++ni)
                    acc[mi][ni] = __builtin_amdgcn_mfma_f32_16x16x32_bf16(
                        af[mi], bfr[ni], acc[mi][ni], 0, 0, 0);
        }
        __syncthreads();
    }
    const int drow = (lane >> 4) * 4;
    const int dcol = lane & 15;
    // raw-partial paths (no bias/act)
    if (kcnt > 1 && blockIdx.z > 0 && Cf2) {
        #pragma unroll
        for (int mi = 0; mi < 4; ++mi)
            #pragma unroll
            for (int ni = 0; ni < 4; ++ni) {
                const int rowb = row0 + wr + mi*16 + drow;
                const int col  = col0 + wc + ni*16 + dcol;
                #pragma unroll
                for (int r = 0; r < 4; ++r)
                    Cf2[(size_t)(rowb + r) * N + col] = acc[mi][ni][r];
            }
        return;
    }
    float* Cfz = Cf;
    if (kcnt > 1 && !Cf2) Cfz = Cf + (size_t)blockIdx.z * ((size_t)M * N);
    #pragma unroll
    for (int mi = 0; mi < 4; ++mi) {
        #pragma unroll
        for (int ni = 0; ni < 4; ++ni) {
            const int rowb = row0 + wr + mi*16 + drow;
            const int col  = col0 + wc + ni*16 + dcol;
            float bv = bias ? ld1(bias, boff + col, f) : 0.f;
            float vv[4];
            #pragma unroll
            for (int r = 0; r < 4; ++r) {
                float v = acc[mi][ni][r] + bv;
                if (act == 1) v = (v > 15.f) ? v : log1pf(__expf(v));
                else if (act == 2) v = 0.5f * v * (1.f + erff(v * 0.70710678118f));
                vv[r] = v;
            }
            if (accum) {
                #pragma unroll
                for (int r = 0; r < 4; ++r)
                    Cf[(size_t)(rowb + r) * N + col] += vv[r];
            } else if (Cf) {
                #pragma unroll
                for (int r = 0; r < 4; ++r)
                    Cfz[(size_t)(rowb + r) * N + col] = vv[r];
            } else {
                if (Cb) {
                    #pragma unroll
                    for (int r = 0; r < 4; ++r)
                        Cb[(size_t)(rowb + r) * N + col] = f2b(vv[r]);
                }
                if (CbT) {
                    u16x4 pk;
                    #pragma unroll
                    for (int r = 0; r < 4; ++r) pk[r] = f2b(vv[r]);
                    *(u16x4*)(CbT + (size_t)col * M + rowb) = pk;
                }
            }
        }
    }
}

// Both-dirs conv + silu; also rewrites xz z-cols in place as silu(z).
// xz_both [ROWS][2048]: 0..511 x_f | 512..1023 z_f | 1024..1535 x_r | 1536..2047 z_r
__global__ __launch_bounds__(256)
void conv_both(u16* __restrict__ xz, const void* __restrict__ cw,
               const void* __restrict__ cb, u16* __restrict__ xc, int e,
               const int* __restrict__ flag)
{
    const int f = *flag;
    int idx = blockIdx.x * 256 + threadIdx.x;   // ROWS*1024
    int row = idx >> 10;
    int c = idx & 1023;
    int dir = c >> 9, d = c & 511;
    int l = row & (LL - 1);
    size_t base = (size_t)row * 2048 + dir * 1024;
    float xcur = b2f(xz[base + d]);
    int dsign = dir ? 1 : -1;
    int ln = l + dsign;
    float xnb = (ln >= 0 && ln < LL) ? b2f(xz[base + dsign*2048 + d]) : 0.f;
    size_t co = (size_t)(e*2 + dir) * 1024 + 2*d;
    float v = ld1(cw, co, f) * xnb + ld1(cw, co + 1, f) * xcur
            + ld1(cb, (size_t)(e*2 + dir)*512 + d, f);
    xc[(size_t)row * 1024 + c] = f2b(v / (1.f + __expf(-v)));
    float z = b2f(xz[base + 512 + d]);
    xz[base + 512 + d] = f2b(z / (1.f + __expf(-z)));
}

// [8192][C] -> [C][8192] bf16 transpose, 64x64 LDS tiles. grid (C/64, 128).
__global__ __launch_bounds__(256)
void transp(const u16* __restrict__ src, u16* __restrict__ dst, int C)
{
    __shared__ u16 t[64][72];
    const int c0 = blockIdx.x * 64, r0 = blockIdx.y * 64;
    const int rr = threadIdx.x >> 3, cc = (threadIdx.x & 7) * 8;
    #pragma unroll
    for (int i = 0; i < 2; ++i) {
        uint4 v = *(const uint4*)(src + (size_t)(r0 + rr + i*32) * C + c0 + cc);
        *(uint4*)&t[rr + i*32][cc] = v;
    }
    __syncthreads();
    const int tc = threadIdx.x >> 3, tr = (threadIdx.x & 7) * 8;
    #pragma unroll
    for (int i = 0; i < 2; ++i) {
        u16 tmp[8];
        #pragma unroll
        for (int j = 0; j < 8; ++j) tmp[j] = t[tr + j][tc + i*32];
        *(uint4*)(dst + (size_t)(c0 + tc + i*32) * 8192 + r0 + tr) = *(uint4*)tmp;
    }
}

// Direction-templated scan body (Round-3 verified form): depth-1 prefetch with
// loads issued BEFORE the serial chunk compute; 8-step chunks, 16B vector loads,
// DPP reduction, one masked store per chunk (lane j holds step j's output).
template<int DIR>
__device__ __forceinline__ void scan_dir(
    const u16* __restrict__ dtp, const u16* __restrict__ xcp,
    const u16* __restrict__ Bp, const u16* __restrict__ Cp,
    const u16* __restrict__ zp, u16* __restrict__ gp,
    float Av, float Dv, int lane)
{
    float h = 0.f;
    int lb = DIR ? (LL - 8) : 0;
    const int stp = DIR ? -8 : 8;
    uint4 d8 = *(const uint4*)(dtp + lb);
    uint4 x8 = *(const uint4*)(xcp + lb);
    uint4 B8 = *(const uint4*)(Bp + lb);
    uint4 C8 = *(const uint4*)(Cp + lb);
    for (int it = 0; it < LL / 8; ++it) {
        const int lbn = lb + stp;
        uint4 nd = d8, nx = x8, nB = B8, nC = C8;
        if (it < LL / 8 - 1) {
            nd = *(const uint4*)(dtp + lbn);
            nx = *(const uint4*)(xcp + lbn);
            nB = *(const uint4*)(Bp + lbn);
            nC = *(const uint4*)(Cp + lbn);
        }
        float keep = 0.f;
        #pragma unroll
        for (int jj = 0; jj < 8; ++jj) {
            const int j = DIR ? (7 - jj) : jj;
            float dtv = bf_elem(d8, j);
            float xv  = bf_elem(x8, j);
            float Bn  = bf_elem(B8, j);
            float Cn  = bf_elem(C8, j);
            h = __expf(dtv * Av) * h + (dtv * xv) * Bn;
            float c = red16(h * Cn) + Dv * xv;
            keep = (lane == j) ? c : keep;
        }
        if (lane < 8) {
            float zs = b2f(zp[(lb + lane) * 2048]);   // pre-silu'd z
            gp[(lb + lane) * 1024] = f2b(keep * zs);
        }
        d8 = nd; x8 = nx; B8 = nB; C8 = nC;
        lb = lbn;
    }
}

// Both-dirs selective scan. Inputs L-contiguous: dtT/xcT [1024][8192], projT [128][8192].
// z read scalar from xz (row-major). Output g row-major [8192][1024]. 1024 blocks.
__global__ __launch_bounds__(256)
void ssm_scan(u16* __restrict__ g, const u16* __restrict__ dtT,
              const u16* __restrict__ xcT, const u16* __restrict__ projT,
              const u16* __restrict__ xz,
              const void* __restrict__ A_log, const void* __restrict__ Dsk,
              int e, const int* __restrict__ flag)
{
    const int f = *flag;
    const int lane = threadIdx.x & 15;
    const int gg = blockIdx.x * 16 + (threadIdx.x >> 4);   // 0..16383
    const int dir = gg >> 13;
    const int rem = gg & 8191;
    const int b = rem >> 9, d = rem & 511;
    const int ed = e * 2 + dir;
    const float Av = -__expf(ld1(A_log, (size_t)ed * 8192 + d * 16 + lane, f));
    const float Dv = ld1(Dsk, (size_t)ed * 512 + d, f);
    const int col = dir * 512 + d;
    const size_t tb = (size_t)col * 8192 + b * 512;
    const u16* dtp = dtT + tb;
    const u16* xcp = xcT + tb;
    const u16* Bp  = projT + (size_t)(dir * 64 + 32 + lane) * 8192 + b * 512;
    const u16* Cp  = Bp + (size_t)16 * 8192;
    u16* gp = g + (size_t)b * LL * 1024 + col;
    const u16* zp = xz + (size_t)b * LL * 2048 + dir * 1024 + 512 + d;
    if (dir == 0) scan_dir<0>(dtp, xcp, Bp, Cp, zp, gp, Av, Dv, lane);
    else          scan_dir<1>(dtp, xcp, Bp, Cp, zp, gp, Av, Dv, lane);
}

// Row LayerNorm; optional extra f32 input Xf2 (split-K partial) and f32
// side-output accf (pre-rounding, replaces acc_init).
__global__ __launch_bounds__(256)
void lnorm(const u16* __restrict__ Xb, const float* __restrict__ Xf,
           const float* __restrict__ Xf2,
           const void* __restrict__ w, size_t wo, const void* __restrict__ b, size_t bo,
           void* __restrict__ out, int omode, float* __restrict__ accf,
           const int* __restrict__ flag)
{
    const int f = *flag;
    int wid = (blockIdx.x * 256 + threadIdx.x) >> 6;
    int lane = threadIdx.x & 63;
    size_t base = (size_t)wid * DD;
    float v[8];
    float s = 0.f;
    #pragma unroll
    for (int i = 0; i < 8; ++i) {
        int c = lane + i*64;
        float t = 0.f;
        if (Xb) t += b2f(Xb[base + c]);
        if (Xf) t += Xf[base + c];
        if (Xf2) t += Xf2[base + c];
        v[i] = t; s += t;
    }
    #pragma unroll
    for (int off = 32; off > 0; off >>= 1) s += __shfl_xor(s, off);
    float mean = s * (1.f/512.f);
    float var = 0.f;
    #pragma unroll
    for (int i = 0; i < 8; ++i) { float dlt = v[i] - mean; var += dlt*dlt; }
    #pragma unroll
    for (int off = 32; off > 0; off >>= 1) var += __shfl_xor(var, off);
    float rstd = rsqrtf(var * (1.f/512.f) + 1e-5f);
    #pragma unroll
    for (int i = 0; i < 8; ++i) {
        int c = lane + i*64;
        float o = (v[i] - mean) * rstd * ld1(w, wo + c, f) + ld1(b, bo + c, f);
        if (omode && f) ((float*)out)[base + c] = o;
        else            ((u16*)out)[base + c] = f2b(o);
        if (accf) accf[base + c] = o;
    }
}

extern "C" void kernel_launch(void* const* d_in, const int* in_sizes, int n_in,
                              void* d_out, int out_size, void* d_ws, size_t ws_size,
                              hipStream_t stream)
{
    (void)in_sizes; (void)n_in; (void)out_size; (void)ws_size;
    const void* X       = d_in[0];
    const void* in_w    = d_in[1];
    const void* conv_w  = d_in[2];
    const void* conv_b  = d_in[3];
    const void* xproj_w = d_in[4];
    const void* dt_w    = d_in[5];
    const void* dt_b    = d_in[6];
    const void* A_log   = d_in[7];
    const void* D_skip  = d_in[8];
    const void* out_w   = d_in[9];
    const void* ffn1_w  = d_in[10];
    const void* ffn1_b  = d_in[11];
    const void* ffn2_w  = d_in[12];
    const void* ffn2_b  = d_in[13];
    const void* n1_w    = d_in[14];
    const void* n1_b    = d_in[15];
    const void* n2_w    = d_in[16];
    const void* n2_b    = d_in[17];
    const void* fn_w    = d_in[18];
    const void* fn_b    = d_in[19];

    // Workspace (~123 MB):
    // acc f32 @0 (16M) | cur bf16 @16M (8M) | xz @24M (32M; ffn: ffh)
    // xc @56M (16M; after gemm#2: dtT overlay; ffn: y2 f32)
    // g @72M (16M; gemm2 split-K psum f32; ffn: x1) | proj @88M (2M) | flag @90M
    // wbf @90M+4K (15M) | xcT @105M (16M; after scan: split-K partial psk f32)
    // projT @121M (2M)
    char* p = (char*)d_ws;
    float* acc   = (float*)(p);
    u16*   cur   = (u16*)(p + 16777216);
    u16*   xz    = (u16*)(p + 25165824);
    u16*   xc    = (u16*)(p + 58720256);
    u16*   dtT   = (u16*)(p + 58720256);   // overlays xc (xc dead after gemm#2/3)
    u16*   g     = (u16*)(p + 75497472);
    u16*   proj  = (u16*)(p + 92274688);
    int*   flag  = (int*)(p + 94371840);
    u16*   wbf   = (u16*)(p + 94375936);
    u16*   xcT   = (u16*)(p + 110104576);
    u16*   projT = (u16*)(p + 126881792);
    u16*   ffh   = xz;
    float* y2    = (float*)xc;
    u16*   x1    = g;
    float* psum  = (float*)g;     // 4x8192x128 f32 = 16MB, g dead until scan
    float* psk   = (float*)xcT;   // 8192x512 f32 = 16MB, xcT dead after scan

    detect<<<1, 512, 0, stream>>>((const u16*)X, flag);
    // fused prologue: 12,058,624 threads
    cvt_all<<<47104, 256, 0, stream>>>(X, acc, cur, in_w, ffn1_w, ffn2_w,
                                       xproj_w, dt_w, out_w, wbf, flag);

    for (int e = 0; e < 2; ++e) {
        size_t eo = (size_t)e * 512;
        // xz_both = cur @ [in_f; in_r]^T : [8192,2048]
        gemm_mfma<<<dim3(16,64), 256, 0, stream>>>(
            cur, wbf + W_IN + (size_t)e*1048576, nullptr, xz, nullptr, nullptr,
            ROWS, 2048, 512, nullptr, 0, 0, 0, 1, flag);
        conv_both<<<ROWS*1024/256, 256, 0, stream>>>(xz, conv_w, conv_b, xc, e, flag);
        // xcT = xc^T : [1024][8192]
        transp<<<dim3(16,128), 256, 0, stream>>>(xc, xcT, 1024);
        // proj_both = xc_both @ XP2^T : [8192,128], split-K=4 into psum (g region)
        gemm_mfma<<<dim3(1,64,4), 256, 0, stream>>>(
            xc, wbf + W_XP + (size_t)e*131072, psum, nullptr, nullptr, nullptr,
            ROWS, 128, 1024, nullptr, 0, 0, 0, 4, flag);
        ksum<<<4096, 256, 0, stream>>>(psum, proj);
        transp<<<dim3(2,128), 256, 0, stream>>>(proj, projT, 128);
        // dtT = softplus(proj_both @ DT2^T + dt_b)^T : [1024][8192] (over xc region)
        gemm_mfma<<<dim3(8,64), 256, 0, stream>>>(
            proj, wbf + W_DT + (size_t)e*131072, nullptr, nullptr, dtT, nullptr,
            ROWS, 1024, 128, dt_b, (size_t)e*1024, 1, 0, 1, flag);
        ssm_scan<<<1024, 256, 0, stream>>>(g, dtT, xcT, projT, xz,
                                           A_log, D_skip, e, flag);
        // acc += g_both @ OUT2^T : [8192,512], split-K=2 (z=0 accum, z=1 -> psk)
        gemm_mfma<<<dim3(4,64,2), 256, 0, stream>>>(
            g, wbf + W_OUT + (size_t)e*524288, acc, nullptr, nullptr, psk,
            ROWS, 512, 1024, nullptr, 0, 0, 1, 2, flag);
        // lnorm1 sums acc + psk
        lnorm<<<2048, 256, 0, stream>>>(nullptr, acc, psk, n1_w, eo, n1_b, eo,
                                        x1, 0, nullptr, flag);
        gemm_mfma<<<dim3(16,64), 256, 0, stream>>>(
            x1, wbf + W_FF1 + (size_t)e*1048576, nullptr, ffh, nullptr, nullptr,
            ROWS, 2048, 512, ffn1_b, (size_t)e*2048, 2, 0, 1, flag);
        // y2 = ffh @ FF2^T + bias : split-K=2 (z=0 -> y2 with bias, z=1 -> psk)
        gemm_mfma<<<dim3(4,64,2), 256, 0, stream>>>(
            ffh, wbf + W_FF2 + (size_t)e*1048576, y2, nullptr, nullptr, psk,
            ROWS, 512, 2048, ffn2_b, eo, 0, 0, 2, flag);
        // lnorm2 sums x1 + y2 + psk; e=0: also write acc f32 (replaces acc_init)
        lnorm<<<2048, 256, 0, stream>>>(x1, y2, psk, n2_w, eo, n2_b, eo, cur, 0,
                                        (e == 0) ? acc : nullptr, flag);
    }
    lnorm<<<2048, 256, 0, stream>>>(cur, nullptr, nullptr, fn_w, 0, fn_b, 0,
                                    d_out, 1, nullptr, flag);
}